// Round 9
// baseline (3428.510 us; speedup 1.0000x reference)
//
#include <hip/hip_runtime.h>
#include <float.h>

#define N_TOK 262144
#define N_E   1024
#define E_DIM 64
#define BETA  0.25f
#define BLK   256     // threads per block == tokens per block
#define NLDS  24      // x[40..63] in volatile LDS column (25 KB -> 6 blk/CU)

typedef float f32x64 __attribute__((ext_vector_type(64)));

// ---------------------------------------------------------------------------
// Bit-exact replica of numpy f32 sum-of-squares over 64 elements (register
// form, used by vq_prep). numpy reduce: out = q0 + pairwise_sum(q[1:], 63):
//   r[i] = b[i] (i=0..7); for blk=8..48 step 8: r[i] += b[blk+i];
//   res = ((r0+r1)+(r2+r3))+((r4+r5)+(r6+r7)); res += b[56..62] seq;
//   out = q0 + res;   (b[i] = v[1+i], all ops individually rounded)
// DO NOT change the op order: index bit-exactness depends on it.
// ---------------------------------------------------------------------------
__device__ __forceinline__ float np_sumsq64_v(f32x64 v)
{
    float r0 = __fmul_rn(v[1], v[1]);
    float r1 = __fmul_rn(v[2], v[2]);
    float r2 = __fmul_rn(v[3], v[3]);
    float r3 = __fmul_rn(v[4], v[4]);
    float r4 = __fmul_rn(v[5], v[5]);
    float r5 = __fmul_rn(v[6], v[6]);
    float r6 = __fmul_rn(v[7], v[7]);
    float r7 = __fmul_rn(v[8], v[8]);
#define VQ_ACC8(blk)                                                     \
    r0 = __fadd_rn(r0, __fmul_rn(v[1 + (blk)], v[1 + (blk)]));          \
    r1 = __fadd_rn(r1, __fmul_rn(v[2 + (blk)], v[2 + (blk)]));          \
    r2 = __fadd_rn(r2, __fmul_rn(v[3 + (blk)], v[3 + (blk)]));          \
    r3 = __fadd_rn(r3, __fmul_rn(v[4 + (blk)], v[4 + (blk)]));          \
    r4 = __fadd_rn(r4, __fmul_rn(v[5 + (blk)], v[5 + (blk)]));          \
    r5 = __fadd_rn(r5, __fmul_rn(v[6 + (blk)], v[6 + (blk)]));          \
    r6 = __fadd_rn(r6, __fmul_rn(v[7 + (blk)], v[7 + (blk)]));          \
    r7 = __fadd_rn(r7, __fmul_rn(v[8 + (blk)], v[8 + (blk)]))
    VQ_ACC8(8); VQ_ACC8(16); VQ_ACC8(24); VQ_ACC8(32); VQ_ACC8(40); VQ_ACC8(48);
#undef VQ_ACC8
    float tA  = __fadd_rn(__fadd_rn(r0, r1), __fadd_rn(r2, r3));
    float tB  = __fadd_rn(__fadd_rn(r4, r5), __fadd_rn(r6, r7));
    float res = __fadd_rn(tA, tB);
    res = __fadd_rn(res, __fmul_rn(v[57], v[57]));
    res = __fadd_rn(res, __fmul_rn(v[58], v[58]));
    res = __fadd_rn(res, __fmul_rn(v[59], v[59]));
    res = __fadd_rn(res, __fmul_rn(v[60], v[60]));
    res = __fadd_rn(res, __fmul_rn(v[61], v[61]));
    res = __fadd_rn(res, __fmul_rn(v[62], v[62]));
    res = __fadd_rn(res, __fmul_rn(v[63], v[63]));
    return __fadd_rn(__fmul_rn(v[0], v[0]), res);
}

__global__ __launch_bounds__(256) void vq_prep(const float* __restrict__ cb,
                                               float* __restrict__ scn,
                                               float* __restrict__ loss_slot)
{
    int j = blockIdx.x * 256 + threadIdx.x;
    if (j < N_E) {
        const float* c = cb + (size_t)j * E_DIM;
        f32x64 cr;
#pragma unroll
        for (int k = 0; k < E_DIM; k += 4) {
            float4 v = *(const float4*)(c + k);
            cr[k] = v.x; cr[k + 1] = v.y; cr[k + 2] = v.z; cr[k + 3] = v.w;
        }
        scn[j] = np_sumsq64_v(cr);
    }
    if (blockIdx.x == 0 && threadIdx.x == 0) *loss_slot = 0.f;
}

// ---------------------------------------------------------------------------
// Main. One token/thread. Hybrid x-placement: k=0..39 in named VGPRs,
// k=40..63 in a VOLATILE thread-private LDS column. volatile is load-bearing:
// round 8's non-volatile version was store-forwarded + eliminated by the
// compiler (LDS_Block_Size 512, scratch spill back, 752us). volatile forces
// real ds_write/ds_read and blocks LICM from re-inflating register pressure.
// j-batch of 8 chains: each x operand feeds 8 FMAs -> LDS pipe ~119us total
// vs 218us VALU floor. launch_bounds(256,6): VGPR cap ~85 (live ~60), LDS
// 25KB -> 6 blocks/CU = 24 waves/CU.
// Bit-exact np f32 pipeline (frozen from passing r3/r6):
//   m_j: single fmaf chain, k = 0..63 strictly ascending
//   d_j = f32( f32(sx + scn_j) - f32(2*m_j) ); argmin strict <, j ascending.
// ---------------------------------------------------------------------------
__global__ __launch_bounds__(BLK, 6)
void vq_main(const float* __restrict__ x,
             const float* __restrict__ cb,
             const float* __restrict__ scn,
             float* __restrict__ xq_out,
             float* __restrict__ loss_out,
             float* __restrict__ idx_out)
{
    volatile __shared__ float At[NLDS][BLK];   // x[40..63] columns, 24.6 KB
    __shared__ float red[4];

    const int t   = threadIdx.x;
    const int tok = blockIdx.x * BLK + t;

    float x0,  x1,  x2,  x3,  x4,  x5,  x6,  x7,  x8,  x9;
    float x10, x11, x12, x13, x14, x15, x16, x17, x18, x19;
    float x20, x21, x22, x23, x24, x25, x26, x27, x28, x29;
    float x30, x31, x32, x33, x34, x35, x36, x37, x38, x39;

#define XV_0 x0
#define XV_1 x1
#define XV_2 x2
#define XV_3 x3
#define XV_4 x4
#define XV_5 x5
#define XV_6 x6
#define XV_7 x7
#define XV_8 x8
#define XV_9 x9
#define XV_10 x10
#define XV_11 x11
#define XV_12 x12
#define XV_13 x13
#define XV_14 x14
#define XV_15 x15
#define XV_16 x16
#define XV_17 x17
#define XV_18 x18
#define XV_19 x19
#define XV_20 x20
#define XV_21 x21
#define XV_22 x22
#define XV_23 x23
#define XV_24 x24
#define XV_25 x25
#define XV_26 x26
#define XV_27 x27
#define XV_28 x28
#define XV_29 x29
#define XV_30 x30
#define XV_31 x31
#define XV_32 x32
#define XV_33 x33
#define XV_34 x34
#define XV_35 x35
#define XV_36 x36
#define XV_37 x37
#define XV_38 x38
#define XV_39 x39
#define XV_40 At[0][t]
#define XV_41 At[1][t]
#define XV_42 At[2][t]
#define XV_43 At[3][t]
#define XV_44 At[4][t]
#define XV_45 At[5][t]
#define XV_46 At[6][t]
#define XV_47 At[7][t]
#define XV_48 At[8][t]
#define XV_49 At[9][t]
#define XV_50 At[10][t]
#define XV_51 At[11][t]
#define XV_52 At[12][t]
#define XV_53 At[13][t]
#define XV_54 At[14][t]
#define XV_55 At[15][t]
#define XV_56 At[16][t]
#define XV_57 At[17][t]
#define XV_58 At[18][t]
#define XV_59 At[19][t]
#define XV_60 At[20][t]
#define XV_61 At[21][t]
#define XV_62 At[22][t]
#define XV_63 At[23][t]
#define XV(k) XV_##k

    // ---- stage x row: 10 float4 -> regs, 6 float4 -> own LDS column ----
    {
        const float* xrow = x + (size_t)tok * E_DIM;
        float4 q;
        q = *(const float4*)(xrow +  0); x0  = q.x; x1  = q.y; x2  = q.z; x3  = q.w;
        q = *(const float4*)(xrow +  4); x4  = q.x; x5  = q.y; x6  = q.z; x7  = q.w;
        q = *(const float4*)(xrow +  8); x8  = q.x; x9  = q.y; x10 = q.z; x11 = q.w;
        q = *(const float4*)(xrow + 12); x12 = q.x; x13 = q.y; x14 = q.z; x15 = q.w;
        q = *(const float4*)(xrow + 16); x16 = q.x; x17 = q.y; x18 = q.z; x19 = q.w;
        q = *(const float4*)(xrow + 20); x20 = q.x; x21 = q.y; x22 = q.z; x23 = q.w;
        q = *(const float4*)(xrow + 24); x24 = q.x; x25 = q.y; x26 = q.z; x27 = q.w;
        q = *(const float4*)(xrow + 28); x28 = q.x; x29 = q.y; x30 = q.z; x31 = q.w;
        q = *(const float4*)(xrow + 32); x32 = q.x; x33 = q.y; x34 = q.z; x35 = q.w;
        q = *(const float4*)(xrow + 36); x36 = q.x; x37 = q.y; x38 = q.z; x39 = q.w;
        q = *(const float4*)(xrow + 40); At[0][t]  = q.x; At[1][t]  = q.y; At[2][t]  = q.z; At[3][t]  = q.w;
        q = *(const float4*)(xrow + 44); At[4][t]  = q.x; At[5][t]  = q.y; At[6][t]  = q.z; At[7][t]  = q.w;
        q = *(const float4*)(xrow + 48); At[8][t]  = q.x; At[9][t]  = q.y; At[10][t] = q.z; At[11][t] = q.w;
        q = *(const float4*)(xrow + 52); At[12][t] = q.x; At[13][t] = q.y; At[14][t] = q.z; At[15][t] = q.w;
        q = *(const float4*)(xrow + 56); At[16][t] = q.x; At[17][t] = q.y; At[18][t] = q.z; At[19][t] = q.w;
        q = *(const float4*)(xrow + 60); At[20][t] = q.x; At[21][t] = q.y; At[22][t] = q.z; At[23][t] = q.w;
    }

    // ---- sx: numpy pairwise order (frozen); LDS values read via temps ----
    float sx;
    {
        float e;
#define Q(k)  (e = XV(k), __fmul_rn(e, e))
        float r0 = Q(1), r1 = Q(2), r2 = Q(3), r3 = Q(4);
        float r4 = Q(5), r5 = Q(6), r6 = Q(7), r7 = Q(8);
        r0 = __fadd_rn(r0, Q(9));  r1 = __fadd_rn(r1, Q(10));
        r2 = __fadd_rn(r2, Q(11)); r3 = __fadd_rn(r3, Q(12));
        r4 = __fadd_rn(r4, Q(13)); r5 = __fadd_rn(r5, Q(14));
        r6 = __fadd_rn(r6, Q(15)); r7 = __fadd_rn(r7, Q(16));
        r0 = __fadd_rn(r0, Q(17)); r1 = __fadd_rn(r1, Q(18));
        r2 = __fadd_rn(r2, Q(19)); r3 = __fadd_rn(r3, Q(20));
        r4 = __fadd_rn(r4, Q(21)); r5 = __fadd_rn(r5, Q(22));
        r6 = __fadd_rn(r6, Q(23)); r7 = __fadd_rn(r7, Q(24));
        r0 = __fadd_rn(r0, Q(25)); r1 = __fadd_rn(r1, Q(26));
        r2 = __fadd_rn(r2, Q(27)); r3 = __fadd_rn(r3, Q(28));
        r4 = __fadd_rn(r4, Q(29)); r5 = __fadd_rn(r5, Q(30));
        r6 = __fadd_rn(r6, Q(31)); r7 = __fadd_rn(r7, Q(32));
        r0 = __fadd_rn(r0, Q(33)); r1 = __fadd_rn(r1, Q(34));
        r2 = __fadd_rn(r2, Q(35)); r3 = __fadd_rn(r3, Q(36));
        r4 = __fadd_rn(r4, Q(37)); r5 = __fadd_rn(r5, Q(38));
        r6 = __fadd_rn(r6, Q(39)); r7 = __fadd_rn(r7, Q(40));
        r0 = __fadd_rn(r0, Q(41)); r1 = __fadd_rn(r1, Q(42));
        r2 = __fadd_rn(r2, Q(43)); r3 = __fadd_rn(r3, Q(44));
        r4 = __fadd_rn(r4, Q(45)); r5 = __fadd_rn(r5, Q(46));
        r6 = __fadd_rn(r6, Q(47)); r7 = __fadd_rn(r7, Q(48));
        r0 = __fadd_rn(r0, Q(49)); r1 = __fadd_rn(r1, Q(50));
        r2 = __fadd_rn(r2, Q(51)); r3 = __fadd_rn(r3, Q(52));
        r4 = __fadd_rn(r4, Q(53)); r5 = __fadd_rn(r5, Q(54));
        r6 = __fadd_rn(r6, Q(55)); r7 = __fadd_rn(r7, Q(56));
        float tA  = __fadd_rn(__fadd_rn(r0, r1), __fadd_rn(r2, r3));
        float tB  = __fadd_rn(__fadd_rn(r4, r5), __fadd_rn(r6, r7));
        float res = __fadd_rn(tA, tB);
        res = __fadd_rn(res, Q(57));
        res = __fadd_rn(res, Q(58));
        res = __fadd_rn(res, Q(59));
        res = __fadd_rn(res, Q(60));
        res = __fadd_rn(res, Q(61));
        res = __fadd_rn(res, Q(62));
        res = __fadd_rn(res, Q(63));
        sx = __fadd_rn(Q(0), res);
#undef Q
    }

    float dmin = FLT_MAX;
    int   imin = 0;

    // per-k step: 8 fmaf (one per j-chain); per-chain k order strictly asc.
#define FK(k) {                                   \
        const float xv = XV(k);                   \
        m0 = fmaf(xv, c0[k], m0);                 \
        m1 = fmaf(xv, c1[k], m1);                 \
        m2 = fmaf(xv, c2[k], m2);                 \
        m3 = fmaf(xv, c3[k], m3);                 \
        m4 = fmaf(xv, c4[k], m4);                 \
        m5 = fmaf(xv, c5[k], m5);                 \
        m6 = fmaf(xv, c6[k], m6);                 \
        m7 = fmaf(xv, c7[k], m7);                 \
    }
#define DCHK(jl, mv) {                                                       \
    float d = __fsub_rn(__fadd_rn(sx, scn[j0 + (jl)]), __fmul_rn(2.0f, mv)); \
    if (d < dmin) { dmin = d; imin = j0 + (jl); }                            \
}

#pragma clang loop unroll(disable)
    for (int j0 = 0; j0 < N_E; j0 += 8) {
        const float* c0 = cb + (size_t)j0 * E_DIM;   // wave-uniform
        const float* c1 = c0 + E_DIM;
        const float* c2 = c1 + E_DIM;
        const float* c3 = c2 + E_DIM;
        const float* c4 = c3 + E_DIM;
        const float* c5 = c4 + E_DIM;
        const float* c6 = c5 + E_DIM;
        const float* c7 = c6 + E_DIM;
        float m0 = 0.f, m1 = 0.f, m2 = 0.f, m3 = 0.f;
        float m4 = 0.f, m5 = 0.f, m6 = 0.f, m7 = 0.f;
        FK(0)  FK(1)  FK(2)  FK(3)  FK(4)  FK(5)  FK(6)  FK(7)
        FK(8)  FK(9)  FK(10) FK(11) FK(12) FK(13) FK(14) FK(15)
        FK(16) FK(17) FK(18) FK(19) FK(20) FK(21) FK(22) FK(23)
        FK(24) FK(25) FK(26) FK(27) FK(28) FK(29) FK(30) FK(31)
        FK(32) FK(33) FK(34) FK(35) FK(36) FK(37) FK(38) FK(39)
        FK(40) FK(41) FK(42) FK(43) FK(44) FK(45) FK(46) FK(47)
        FK(48) FK(49) FK(50) FK(51) FK(52) FK(53) FK(54) FK(55)
        FK(56) FK(57) FK(58) FK(59) FK(60) FK(61) FK(62) FK(63)
        DCHK(0, m0) DCHK(1, m1) DCHK(2, m2) DCHK(3, m3)
        DCHK(4, m4) DCHK(5, m5) DCHK(6, m6) DCHK(7, m7)
    }
#undef FK
#undef DCHK

    // ---- epilogue: gather winning row (L2-hot), write x_q, fused loss ----
    float lsum = 0.f;
    {
        const float* cmin = cb + (size_t)imin * E_DIM;   // per-lane address
        float*       xq   = xq_out + (size_t)tok * E_DIM;
        float4 cv; float e;
#define LQ(base, a, b, c, d)                                        \
        cv = *(const float4*)(cmin + (base));                       \
        *(float4*)(xq + (base)) = cv;                               \
        e = cv.x - XV(a); lsum = fmaf(e, e, lsum);                  \
        e = cv.y - XV(b); lsum = fmaf(e, e, lsum);                  \
        e = cv.z - XV(c); lsum = fmaf(e, e, lsum);                  \
        e = cv.w - XV(d); lsum = fmaf(e, e, lsum);
        LQ(0,  0, 1, 2, 3)     LQ(4,  4, 5, 6, 7)
        LQ(8,  8, 9, 10, 11)   LQ(12, 12, 13, 14, 15)
        LQ(16, 16, 17, 18, 19) LQ(20, 20, 21, 22, 23)
        LQ(24, 24, 25, 26, 27) LQ(28, 28, 29, 30, 31)
        LQ(32, 32, 33, 34, 35) LQ(36, 36, 37, 38, 39)
        LQ(40, 40, 41, 42, 43) LQ(44, 44, 45, 46, 47)
        LQ(48, 48, 49, 50, 51) LQ(52, 52, 53, 54, 55)
        LQ(56, 56, 57, 58, 59) LQ(60, 60, 61, 62, 63)
#undef LQ
    }
    idx_out[tok] = (float)imin;   // exact integer in f32

    // Loss: 64-lane shuffle tree, cross-wave via LDS, one atomic per block.
    for (int m = 1; m < 64; m <<= 1) lsum += __shfl_xor(lsum, m, 64);
    if ((t & 63) == 0) red[t >> 6] = lsum;
    __syncthreads();
    if (t == 0) {
        float part = (red[0] + red[1]) + (red[2] + red[3]);
        const float scale = (1.0f + BETA) / ((float)N_TOK * (float)E_DIM);
        atomicAdd(loss_out, part * scale);
    }
}

extern "C" void kernel_launch(void* const* d_in, const int* in_sizes, int n_in,
                              void* d_out, int out_size, void* d_ws, size_t ws_size,
                              hipStream_t stream)
{
    const float* x  = (const float*)d_in[0];   // [262144, 64] f32
    const float* cb = (const float*)d_in[1];   // [1024, 64]   f32

    float* out  = (float*)d_out;
    float* xq   = out;                              // 262144*64 floats
    float* loss = out + (size_t)N_TOK * E_DIM;      // 1 float
    float* idx  = loss + 1;                         // 262144 floats

    float* scn = (float*)d_ws;                      // 1024 floats scratch

    vq_prep<<<N_E / 256, 256, 0, stream>>>(cb, scn, loss);
    vq_main<<<N_TOK / BLK, BLK, 0, stream>>>(x, cb, scn, xq, loss, idx);
}

// Round 10
// 742.663 us; speedup vs baseline: 4.6165x; 4.6165x over previous
//
#include <hip/hip_runtime.h>
#include <float.h>

#define N_TOK 262144
#define N_E   1024
#define E_DIM 64
#define BETA  0.25f
#define BLK   256
// Occupancy governor: 36.9 KB LDS -> 4 blocks/CU -> allocator targets
// 4 waves/EU -> VGPR budget 128 (r7 evidence: LDS-capped occupancy is the
// only condition under which this allocator grants >64 VGPRs; all explicit
// hints -- waves_per_eu r4, launch_bounds min r9 -- REDUCED the grant).
#define PAD_FLOATS 9216   // 36864 B

typedef float f32x64 __attribute__((ext_vector_type(64)));

// ---------------------------------------------------------------------------
// Bit-exact replica of numpy f32 sum-of-squares over 64 elements (vq_prep).
// numpy reduce: out = q0 + pairwise_sum(q[1:], 63):
//   r[i] = b[i] (i=0..7); for blk=8..48 step 8: r[i] += b[blk+i];
//   res = ((r0+r1)+(r2+r3))+((r4+r5)+(r6+r7)); res += b[56..62] seq;
//   out = q0 + res;   (b[i] = v[1+i], all ops individually rounded)
// DO NOT change the op order: index bit-exactness depends on it.
// ---------------------------------------------------------------------------
__device__ __forceinline__ float np_sumsq64_v(f32x64 v)
{
    float r0 = __fmul_rn(v[1], v[1]);
    float r1 = __fmul_rn(v[2], v[2]);
    float r2 = __fmul_rn(v[3], v[3]);
    float r3 = __fmul_rn(v[4], v[4]);
    float r4 = __fmul_rn(v[5], v[5]);
    float r5 = __fmul_rn(v[6], v[6]);
    float r6 = __fmul_rn(v[7], v[7]);
    float r7 = __fmul_rn(v[8], v[8]);
#define VQ_ACC8(blk)                                                     \
    r0 = __fadd_rn(r0, __fmul_rn(v[1 + (blk)], v[1 + (blk)]));          \
    r1 = __fadd_rn(r1, __fmul_rn(v[2 + (blk)], v[2 + (blk)]));          \
    r2 = __fadd_rn(r2, __fmul_rn(v[3 + (blk)], v[3 + (blk)]));          \
    r3 = __fadd_rn(r3, __fmul_rn(v[4 + (blk)], v[4 + (blk)]));          \
    r4 = __fadd_rn(r4, __fmul_rn(v[5 + (blk)], v[5 + (blk)]));          \
    r5 = __fadd_rn(r5, __fmul_rn(v[6 + (blk)], v[6 + (blk)]));          \
    r6 = __fadd_rn(r6, __fmul_rn(v[7 + (blk)], v[7 + (blk)]));          \
    r7 = __fadd_rn(r7, __fmul_rn(v[8 + (blk)], v[8 + (blk)]))
    VQ_ACC8(8); VQ_ACC8(16); VQ_ACC8(24); VQ_ACC8(32); VQ_ACC8(40); VQ_ACC8(48);
#undef VQ_ACC8
    float tA  = __fadd_rn(__fadd_rn(r0, r1), __fadd_rn(r2, r3));
    float tB  = __fadd_rn(__fadd_rn(r4, r5), __fadd_rn(r6, r7));
    float res = __fadd_rn(tA, tB);
    res = __fadd_rn(res, __fmul_rn(v[57], v[57]));
    res = __fadd_rn(res, __fmul_rn(v[58], v[58]));
    res = __fadd_rn(res, __fmul_rn(v[59], v[59]));
    res = __fadd_rn(res, __fmul_rn(v[60], v[60]));
    res = __fadd_rn(res, __fmul_rn(v[61], v[61]));
    res = __fadd_rn(res, __fmul_rn(v[62], v[62]));
    res = __fadd_rn(res, __fmul_rn(v[63], v[63]));
    return __fadd_rn(__fmul_rn(v[0], v[0]), res);
}

__global__ __launch_bounds__(256) void vq_prep(const float* __restrict__ cb,
                                               float* __restrict__ scn,
                                               float* __restrict__ loss_slot)
{
    int j = blockIdx.x * 256 + threadIdx.x;
    if (j < N_E) {
        const float* c = cb + (size_t)j * E_DIM;
        f32x64 cr;
#pragma unroll
        for (int k = 0; k < E_DIM; k += 4) {
            float4 v = *(const float4*)(c + k);
            cr[k] = v.x; cr[k + 1] = v.y; cr[k + 2] = v.z; cr[k + 3] = v.w;
        }
        scn[j] = np_sumsq64_v(cr);
    }
    if (blockIdx.x == 0 && threadIdx.x == 0) *loss_slot = 0.f;
}

// ---------------------------------------------------------------------------
// Main. One token/thread, ALL 64 x-values in named VGPRs. The occ_pad LDS
// array exists only to cap occupancy at 4 blocks/CU so the register
// allocator's budget rises to ~128 and the x-row is never spilled (r3-r9:
// every config with an 8-wave/64-VGPR target spilled ~20 floats to scratch,
// costing 25-30% VALU dilution; r7 proved LDS-capped occupancy unlocks >64).
// Inner loop: j-unroll 4, codebook pointers wave-uniform -> s_load broadcast
// operands; zero VMEM, zero LDS in the loop.
// Bit-exact np f32 pipeline (frozen from passing r3/r6):
//   m_j: single fmaf chain, k = 0..63 strictly ascending
//   d_j = f32( f32(sx + scn_j) - f32(2*m_j) ); argmin strict <, j ascending.
// ---------------------------------------------------------------------------
__global__ __launch_bounds__(BLK)
void vq_main(const float* __restrict__ x,
             const float* __restrict__ cb,
             const float* __restrict__ scn,
             float* __restrict__ xq_out,
             float* __restrict__ loss_out,
             float* __restrict__ idx_out)
{
    __shared__ float occ_pad[PAD_FLOATS];   // occupancy governor (36.9 KB)
    __shared__ float red[4];

    const int t   = threadIdx.x;
    const int tok = blockIdx.x * BLK + t;

    float x0,  x1,  x2,  x3,  x4,  x5,  x6,  x7,  x8,  x9;
    float x10, x11, x12, x13, x14, x15, x16, x17, x18, x19;
    float x20, x21, x22, x23, x24, x25, x26, x27, x28, x29;
    float x30, x31, x32, x33, x34, x35, x36, x37, x38, x39;
    float x40, x41, x42, x43, x44, x45, x46, x47, x48, x49;
    float x50, x51, x52, x53, x54, x55, x56, x57, x58, x59;
    float x60, x61, x62, x63;

#define XV_0 x0
#define XV_1 x1
#define XV_2 x2
#define XV_3 x3
#define XV_4 x4
#define XV_5 x5
#define XV_6 x6
#define XV_7 x7
#define XV_8 x8
#define XV_9 x9
#define XV_10 x10
#define XV_11 x11
#define XV_12 x12
#define XV_13 x13
#define XV_14 x14
#define XV_15 x15
#define XV_16 x16
#define XV_17 x17
#define XV_18 x18
#define XV_19 x19
#define XV_20 x20
#define XV_21 x21
#define XV_22 x22
#define XV_23 x23
#define XV_24 x24
#define XV_25 x25
#define XV_26 x26
#define XV_27 x27
#define XV_28 x28
#define XV_29 x29
#define XV_30 x30
#define XV_31 x31
#define XV_32 x32
#define XV_33 x33
#define XV_34 x34
#define XV_35 x35
#define XV_36 x36
#define XV_37 x37
#define XV_38 x38
#define XV_39 x39
#define XV_40 x40
#define XV_41 x41
#define XV_42 x42
#define XV_43 x43
#define XV_44 x44
#define XV_45 x45
#define XV_46 x46
#define XV_47 x47
#define XV_48 x48
#define XV_49 x49
#define XV_50 x50
#define XV_51 x51
#define XV_52 x52
#define XV_53 x53
#define XV_54 x54
#define XV_55 x55
#define XV_56 x56
#define XV_57 x57
#define XV_58 x58
#define XV_59 x59
#define XV_60 x60
#define XV_61 x61
#define XV_62 x62
#define XV_63 x63
#define XV(k) XV_##k

    // ---- load x row: 16 x float4 -> 64 named regs ----
    {
        const float* xrow = x + (size_t)tok * E_DIM;
        float4 q;
        q = *(const float4*)(xrow +  0); x0  = q.x; x1  = q.y; x2  = q.z; x3  = q.w;
        q = *(const float4*)(xrow +  4); x4  = q.x; x5  = q.y; x6  = q.z; x7  = q.w;
        q = *(const float4*)(xrow +  8); x8  = q.x; x9  = q.y; x10 = q.z; x11 = q.w;
        q = *(const float4*)(xrow + 12); x12 = q.x; x13 = q.y; x14 = q.z; x15 = q.w;
        q = *(const float4*)(xrow + 16); x16 = q.x; x17 = q.y; x18 = q.z; x19 = q.w;
        q = *(const float4*)(xrow + 20); x20 = q.x; x21 = q.y; x22 = q.z; x23 = q.w;
        q = *(const float4*)(xrow + 24); x24 = q.x; x25 = q.y; x26 = q.z; x27 = q.w;
        q = *(const float4*)(xrow + 28); x28 = q.x; x29 = q.y; x30 = q.z; x31 = q.w;
        q = *(const float4*)(xrow + 32); x32 = q.x; x33 = q.y; x34 = q.z; x35 = q.w;
        q = *(const float4*)(xrow + 36); x36 = q.x; x37 = q.y; x38 = q.z; x39 = q.w;
        q = *(const float4*)(xrow + 40); x40 = q.x; x41 = q.y; x42 = q.z; x43 = q.w;
        q = *(const float4*)(xrow + 44); x44 = q.x; x45 = q.y; x46 = q.z; x47 = q.w;
        q = *(const float4*)(xrow + 48); x48 = q.x; x49 = q.y; x50 = q.z; x51 = q.w;
        q = *(const float4*)(xrow + 52); x52 = q.x; x53 = q.y; x54 = q.z; x55 = q.w;
        q = *(const float4*)(xrow + 56); x56 = q.x; x57 = q.y; x58 = q.z; x59 = q.w;
        q = *(const float4*)(xrow + 60); x60 = q.x; x61 = q.y; x62 = q.z; x63 = q.w;
    }

    // ---- sx: numpy pairwise order (frozen) ----
    float sx;
    {
#define Q(k) __fmul_rn(XV(k), XV(k))
        float r0 = Q(1), r1 = Q(2), r2 = Q(3), r3 = Q(4);
        float r4 = Q(5), r5 = Q(6), r6 = Q(7), r7 = Q(8);
        r0 = __fadd_rn(r0, Q(9));  r1 = __fadd_rn(r1, Q(10));
        r2 = __fadd_rn(r2, Q(11)); r3 = __fadd_rn(r3, Q(12));
        r4 = __fadd_rn(r4, Q(13)); r5 = __fadd_rn(r5, Q(14));
        r6 = __fadd_rn(r6, Q(15)); r7 = __fadd_rn(r7, Q(16));
        r0 = __fadd_rn(r0, Q(17)); r1 = __fadd_rn(r1, Q(18));
        r2 = __fadd_rn(r2, Q(19)); r3 = __fadd_rn(r3, Q(20));
        r4 = __fadd_rn(r4, Q(21)); r5 = __fadd_rn(r5, Q(22));
        r6 = __fadd_rn(r6, Q(23)); r7 = __fadd_rn(r7, Q(24));
        r0 = __fadd_rn(r0, Q(25)); r1 = __fadd_rn(r1, Q(26));
        r2 = __fadd_rn(r2, Q(27)); r3 = __fadd_rn(r3, Q(28));
        r4 = __fadd_rn(r4, Q(29)); r5 = __fadd_rn(r5, Q(30));
        r6 = __fadd_rn(r6, Q(31)); r7 = __fadd_rn(r7, Q(32));
        r0 = __fadd_rn(r0, Q(33)); r1 = __fadd_rn(r1, Q(34));
        r2 = __fadd_rn(r2, Q(35)); r3 = __fadd_rn(r3, Q(36));
        r4 = __fadd_rn(r4, Q(37)); r5 = __fadd_rn(r5, Q(38));
        r6 = __fadd_rn(r6, Q(39)); r7 = __fadd_rn(r7, Q(40));
        r0 = __fadd_rn(r0, Q(41)); r1 = __fadd_rn(r1, Q(42));
        r2 = __fadd_rn(r2, Q(43)); r3 = __fadd_rn(r3, Q(44));
        r4 = __fadd_rn(r4, Q(45)); r5 = __fadd_rn(r5, Q(46));
        r6 = __fadd_rn(r6, Q(47)); r7 = __fadd_rn(r7, Q(48));
        r0 = __fadd_rn(r0, Q(49)); r1 = __fadd_rn(r1, Q(50));
        r2 = __fadd_rn(r2, Q(51)); r3 = __fadd_rn(r3, Q(52));
        r4 = __fadd_rn(r4, Q(53)); r5 = __fadd_rn(r5, Q(54));
        r6 = __fadd_rn(r6, Q(55)); r7 = __fadd_rn(r7, Q(56));
        float tA  = __fadd_rn(__fadd_rn(r0, r1), __fadd_rn(r2, r3));
        float tB  = __fadd_rn(__fadd_rn(r4, r5), __fadd_rn(r6, r7));
        float res = __fadd_rn(tA, tB);
        res = __fadd_rn(res, Q(57));
        res = __fadd_rn(res, Q(58));
        res = __fadd_rn(res, Q(59));
        res = __fadd_rn(res, Q(60));
        res = __fadd_rn(res, Q(61));
        res = __fadd_rn(res, Q(62));
        res = __fadd_rn(res, Q(63));
        sx = __fadd_rn(Q(0), res);
#undef Q
    }

    float dmin = FLT_MAX;
    int   imin = 0;

    // per-k step: 4 fmaf (one per j-chain); per-chain k order strictly asc.
#define FK(k) {                                   \
        const float xv = XV(k);                   \
        m0 = fmaf(xv, c0[k], m0);                 \
        m1 = fmaf(xv, c1[k], m1);                 \
        m2 = fmaf(xv, c2[k], m2);                 \
        m3 = fmaf(xv, c3[k], m3);                 \
    }
#define DCHK(jl, mv) {                                                       \
    float d = __fsub_rn(__fadd_rn(sx, scn[j0 + (jl)]), __fmul_rn(2.0f, mv)); \
    if (d < dmin) { dmin = d; imin = j0 + (jl); }                            \
}

#pragma clang loop unroll(disable)
    for (int j0 = 0; j0 < N_E; j0 += 4) {
        const float* c0 = cb + (size_t)j0 * E_DIM;   // wave-uniform
        const float* c1 = c0 + E_DIM;
        const float* c2 = c1 + E_DIM;
        const float* c3 = c2 + E_DIM;
        float m0 = 0.f, m1 = 0.f, m2 = 0.f, m3 = 0.f;
        FK(0)  FK(1)  FK(2)  FK(3)  FK(4)  FK(5)  FK(6)  FK(7)
        FK(8)  FK(9)  FK(10) FK(11) FK(12) FK(13) FK(14) FK(15)
        FK(16) FK(17) FK(18) FK(19) FK(20) FK(21) FK(22) FK(23)
        FK(24) FK(25) FK(26) FK(27) FK(28) FK(29) FK(30) FK(31)
        FK(32) FK(33) FK(34) FK(35) FK(36) FK(37) FK(38) FK(39)
        FK(40) FK(41) FK(42) FK(43) FK(44) FK(45) FK(46) FK(47)
        FK(48) FK(49) FK(50) FK(51) FK(52) FK(53) FK(54) FK(55)
        FK(56) FK(57) FK(58) FK(59) FK(60) FK(61) FK(62) FK(63)
        DCHK(0, m0) DCHK(1, m1) DCHK(2, m2) DCHK(3, m3)
    }
#undef FK
#undef DCHK

    // keep the occupancy governor alive (volatile: cannot be eliminated)
    ((volatile float*)occ_pad)[t] = sx;

    // ---- epilogue: gather winning row (L2-hot), write x_q, fused loss ----
    float lsum = 0.f;
    {
        const float* cmin = cb + (size_t)imin * E_DIM;   // per-lane address
        float*       xq   = xq_out + (size_t)tok * E_DIM;
        float4 cv; float e;
#define LQ(base, a, b, c, d)                                        \
        cv = *(const float4*)(cmin + (base));                       \
        *(float4*)(xq + (base)) = cv;                               \
        e = cv.x - XV(a); lsum = fmaf(e, e, lsum);                  \
        e = cv.y - XV(b); lsum = fmaf(e, e, lsum);                  \
        e = cv.z - XV(c); lsum = fmaf(e, e, lsum);                  \
        e = cv.w - XV(d); lsum = fmaf(e, e, lsum);
        LQ(0,  0, 1, 2, 3)     LQ(4,  4, 5, 6, 7)
        LQ(8,  8, 9, 10, 11)   LQ(12, 12, 13, 14, 15)
        LQ(16, 16, 17, 18, 19) LQ(20, 20, 21, 22, 23)
        LQ(24, 24, 25, 26, 27) LQ(28, 28, 29, 30, 31)
        LQ(32, 32, 33, 34, 35) LQ(36, 36, 37, 38, 39)
        LQ(40, 40, 41, 42, 43) LQ(44, 44, 45, 46, 47)
        LQ(48, 48, 49, 50, 51) LQ(52, 52, 53, 54, 55)
        LQ(56, 56, 57, 58, 59) LQ(60, 60, 61, 62, 63)
#undef LQ
    }
    idx_out[tok] = (float)imin;   // exact integer in f32

    // Loss: 64-lane shuffle tree, cross-wave via LDS, one atomic per block.
    for (int m = 1; m < 64; m <<= 1) lsum += __shfl_xor(lsum, m, 64);
    if ((t & 63) == 0) red[t >> 6] = lsum;
    __syncthreads();
    if (t == 0) {
        float part = (red[0] + red[1]) + (red[2] + red[3]);
        const float scale = (1.0f + BETA) / ((float)N_TOK * (float)E_DIM);
        atomicAdd(loss_out, part * scale);
    }
}

extern "C" void kernel_launch(void* const* d_in, const int* in_sizes, int n_in,
                              void* d_out, int out_size, void* d_ws, size_t ws_size,
                              hipStream_t stream)
{
    const float* x  = (const float*)d_in[0];   // [262144, 64] f32
    const float* cb = (const float*)d_in[1];   // [1024, 64]   f32

    float* out  = (float*)d_out;
    float* xq   = out;                              // 262144*64 floats
    float* loss = out + (size_t)N_TOK * E_DIM;      // 1 float
    float* idx  = loss + 1;                         // 262144 floats

    float* scn = (float*)d_ws;                      // 1024 floats scratch

    vq_prep<<<N_E / 256, 256, 0, stream>>>(cb, scn, loss);
    vq_main<<<N_TOK / BLK, BLK, 0, stream>>>(x, cb, scn, xq, loss, idx);
}